// Round 17
// baseline (94.337 us; speedup 1.0000x reference)
//
#include <hip/hip_runtime.h>
#include <math.h>

// DTW loss: B=128, L1=L2=512, D=16.
// R17 = R15 (4-wave column-split skewed systolic, f32 quad-plane x layout,
// ring-4 asm ds_read pipeline, dependence-carrying counted waits) with
// EP=16 substeps/epoch (WOFF=79, NE=51): halves the per-epoch fixed cost
// (barrier sync + compiler's lgkmcnt(0) drain + packet traffic), which was
// ~500 cy x 99 epochs in R15. All DP/packet/carry logic identical (verified).

#define TL 512
#define TD 16
#define TNB 128
#define BIGF 3.0e38f
#define INFF __builtin_inff()
#define WOFF 79
#define EP 16
#define NE 51

typedef float f32x2 __attribute__((ext_vector_type(2)));
typedef float f32x4 __attribute__((ext_vector_type(4)));

__device__ inline f32x2 pk_fma(f32x2 a, f32x2 b, f32x2 c) {
    f32x2 d;
    asm("v_pk_fma_f32 %0, %1, %2, %3" : "=v"(d) : "v"(a), "v"(b), "v"(c));
    return d;
}
__device__ inline f32x2 pk_mul(f32x2 a, f32x2 b) {
    f32x2 d;
    asm("v_pk_mul_f32 %0, %1, %2" : "=v"(d) : "v"(a), "v"(b));
    return d;
}
__device__ inline float min3f(float a, float b, float c) {
    float d;
    asm("v_min3_f32 %0, %1, %2, %3" : "=v"(d) : "v"(a), "v"(b), "v"(c));
    return d;
}
template<int CTRL, int RM, bool BC>
__device__ inline float dpp_mov(float old_, float src) {
    return __int_as_float(__builtin_amdgcn_update_dpp(
        __float_as_int(old_), __float_as_int(src), CTRL, RM, 0xf, BC));
}

struct XR { f32x4 q0, q1, q2, q3; float sq; };

// issue 5 DS reads for clamped row r from the quad planes (conflict-free)
__device__ inline void xissue(unsigned xb, unsigned sb, int r, XR& x) {
    int rc = r < 0 ? 0 : (r > TL - 1 ? TL - 1 : r);
    unsigned a16 = xb + ((unsigned)rc << 4);
    unsigned a4  = sb + ((unsigned)rc << 2);
    asm volatile("ds_read_b128 %0, %1 offset:0"     : "=v"(x.q0) : "v"(a16));
    asm volatile("ds_read_b128 %0, %1 offset:8192"  : "=v"(x.q1) : "v"(a16));
    asm volatile("ds_read_b128 %0, %1 offset:16384" : "=v"(x.q2) : "v"(a16));
    asm volatile("ds_read_b128 %0, %1 offset:24576" : "=v"(x.q3) : "v"(a16));
    asm volatile("ds_read_b32  %0, %1 offset:0"     : "=v"(x.sq) : "v"(a4));
}

// dependence-carrying counted wait: uses of x.* after this are data-dependent
// on the wait; volatile order keeps it after the matching ds_reads. No
// sched_barrier -> compiler may pipeline independent VALU across it.
#define WAITX(x) asm volatile("s_waitcnt lgkmcnt(10)" \
    : "+v"(x.q0), "+v"(x.q1), "+v"(x.q2), "+v"(x.q3), "+v"(x.sq))

__device__ inline void sub(const XR& x, int r,
                           const f32x2 (&y0)[8], const f32x2 (&y1)[8],
                           f32x2 ys0, f32x2 ys1,
                           float& pv0, float& pv1, float& o1,
                           float bL, float bD, bool lane0) {
    const f32x2* xd = (const f32x2*)&x;          // q0..q3 as 8 f32x2
    f32x2 a0 = ys0, a1 = ys1;                    // {ysq, 0}; y pre-scaled -2
    #pragma unroll
    for (int k = 0; k < 8; ++k) {
        a0 = pk_fma(xd[k], y0[k], a0);
        a1 = pk_fma(xd[k], y1[k], a1);
    }
    const float c0 = x.sq + (a0.x + a0.y);
    const float c1 = x.sq + (a1.x + a1.y);

    float left = dpp_mov<0x138, 0xf, false>(BIGF, pv1);  // DTW[r][j0-1]
    float diag = dpp_mov<0x138, 0xf, false>(BIGF, o1);   // DTW[r-1][j0-1]
    if (lane0) { left = bL; diag = bD; }
    o1 = pv1;

    const float v0 = c0 + min3f(pv0, left, diag);
    const float v1 = c1 + min3f(pv1, v0, pv0);
    const bool valid = (unsigned)r < (unsigned)TL;
    pv0 = valid ? v0 : pv0;
    pv1 = valid ? v1 : pv1;
}

__global__ __launch_bounds__(256, 1) void dtw_split_kernel(const float* __restrict__ s1,
                                                           const float* __restrict__ s2,
                                                           float* __restrict__ ws) {
    const int b   = blockIdx.x;
    const int tid = threadIdx.x;
    const int W   = tid >> 6;    // wave 0..3
    const int l   = tid & 63;

    __shared__ f32x4 xT[4][TL];         // 32 KB quad planes (stride 8 KB)
    __shared__ float sqT[TL];           // 2 KB row sumsq
    __shared__ f32x4 pkt[2][4][4];      // boundary packets (16 rows each)

    const float* s1b = s1 + (size_t)b * TL * TD;

    // stage s1 rows (2/thread) into quad planes + sumsq
    #pragma unroll
    for (int q = 0; q < 2; ++q) {
        const int r = 2 * tid + q;
        const f32x4* src = (const f32x4*)(s1b + r * TD);
        f32x4 q0 = src[0], q1 = src[1], q2 = src[2], q3 = src[3];
        xT[0][r] = q0; xT[1][r] = q1; xT[2][r] = q2; xT[3][r] = q3;
        f32x2 a_ = pk_mul(f32x2{q0.x, q0.y}, f32x2{q0.x, q0.y});
        a_ = pk_fma(f32x2{q0.z, q0.w}, f32x2{q0.z, q0.w}, a_);
        a_ = pk_fma(f32x2{q1.x, q1.y}, f32x2{q1.x, q1.y}, a_);
        a_ = pk_fma(f32x2{q1.z, q1.w}, f32x2{q1.z, q1.w}, a_);
        a_ = pk_fma(f32x2{q2.x, q2.y}, f32x2{q2.x, q2.y}, a_);
        a_ = pk_fma(f32x2{q2.z, q2.w}, f32x2{q2.z, q2.w}, a_);
        a_ = pk_fma(f32x2{q3.x, q3.y}, f32x2{q3.x, q3.y}, a_);
        a_ = pk_fma(f32x2{q3.z, q3.w}, f32x2{q3.z, q3.w}, a_);
        sqT[r] = a_.x + a_.y;
    }
    if (tid < 128) ((float*)pkt)[tid] = BIGF;

    // y tile: 2 cols/lane; prescale -2; acc seeds {ysq, 0}
    const int j0 = 2 * (64 * W + l);
    f32x2 y0[8], y1[8];
    const float* yp0 = s2 + ((size_t)b * TL + j0) * TD;
    #pragma unroll
    for (int k = 0; k < 8; ++k) {
        y0[k] = *(const f32x2*)(yp0 + 2 * k);
        y1[k] = *(const f32x2*)(yp0 + TD + 2 * k);
    }
    f32x2 s0a = pk_mul(y0[0], y0[0]), s1a = pk_mul(y1[0], y1[0]);
    #pragma unroll
    for (int k = 1; k < 8; ++k) {
        s0a = pk_fma(y0[k], y0[k], s0a);
        s1a = pk_fma(y1[k], y1[k], s1a);
    }
    const f32x2 ys0 = {s0a.x + s0a.y, 0.f};
    const f32x2 ys1 = {s1a.x + s1a.y, 0.f};
    #pragma unroll
    for (int k = 0; k < 8; ++k) {
        y0[k] = pk_mul(y0[k], f32x2{-2.f, -2.f});
        y1[k] = pk_mul(y1[k], f32x2{-2.f, -2.f});
    }

    __syncthreads();

    const unsigned xb = (unsigned)(uintptr_t)&xT[0][0];
    const unsigned sb = (unsigned)(uintptr_t)&sqT[0];
    const int gL = WOFF * W + l;
    const bool lane0 = (l == 0);
    float pv0 = INFF, pv1 = INFF, o1 = INFF;
    float carry = (W == 0) ? 0.f : BIGF;   // lane0 diag seed DTW[-1][-1]=0

    XR x0, x1, x2, x3;
    xissue(xb, sb, 0 - gL, x0);
    xissue(xb, sb, 1 - gL, x1);
    xissue(xb, sb, 2 - gL, x2);

    for (int e = 0; e < NE; ++e) {
        float lb[16];
        #pragma unroll
        for (int m = 0; m < 16; ++m) lb[m] = BIGF;
        if (W > 0) {
            #pragma unroll
            for (int p = 0; p < 4; ++p) {
                f32x4 pk = pkt[(e + 1) & 1][W - 1][p];
                lb[4 * p + 0] = pk.x; lb[4 * p + 1] = pk.y;
                lb[4 * p + 2] = pk.z; lb[4 * p + 3] = pk.w;
            }
        }
        const int rb = EP * e - gL;
        float t[16];

        WAITX(x0); xissue(xb, sb, rb + 3,  x3);
        sub(x0, rb + 0,  y0, y1, ys0, ys1, pv0, pv1, o1, lb[0],  carry,  lane0); t[0]  = pv1;
        WAITX(x1); xissue(xb, sb, rb + 4,  x0);
        sub(x1, rb + 1,  y0, y1, ys0, ys1, pv0, pv1, o1, lb[1],  lb[0],  lane0); t[1]  = pv1;
        WAITX(x2); xissue(xb, sb, rb + 5,  x1);
        sub(x2, rb + 2,  y0, y1, ys0, ys1, pv0, pv1, o1, lb[2],  lb[1],  lane0); t[2]  = pv1;
        WAITX(x3); xissue(xb, sb, rb + 6,  x2);
        sub(x3, rb + 3,  y0, y1, ys0, ys1, pv0, pv1, o1, lb[3],  lb[2],  lane0); t[3]  = pv1;
        WAITX(x0); xissue(xb, sb, rb + 7,  x3);
        sub(x0, rb + 4,  y0, y1, ys0, ys1, pv0, pv1, o1, lb[4],  lb[3],  lane0); t[4]  = pv1;
        WAITX(x1); xissue(xb, sb, rb + 8,  x0);
        sub(x1, rb + 5,  y0, y1, ys0, ys1, pv0, pv1, o1, lb[5],  lb[4],  lane0); t[5]  = pv1;
        WAITX(x2); xissue(xb, sb, rb + 9,  x1);
        sub(x2, rb + 6,  y0, y1, ys0, ys1, pv0, pv1, o1, lb[6],  lb[5],  lane0); t[6]  = pv1;
        WAITX(x3); xissue(xb, sb, rb + 10, x2);
        sub(x3, rb + 7,  y0, y1, ys0, ys1, pv0, pv1, o1, lb[7],  lb[6],  lane0); t[7]  = pv1;
        WAITX(x0); xissue(xb, sb, rb + 11, x3);
        sub(x0, rb + 8,  y0, y1, ys0, ys1, pv0, pv1, o1, lb[8],  lb[7],  lane0); t[8]  = pv1;
        WAITX(x1); xissue(xb, sb, rb + 12, x0);
        sub(x1, rb + 9,  y0, y1, ys0, ys1, pv0, pv1, o1, lb[9],  lb[8],  lane0); t[9]  = pv1;
        WAITX(x2); xissue(xb, sb, rb + 13, x1);
        sub(x2, rb + 10, y0, y1, ys0, ys1, pv0, pv1, o1, lb[10], lb[9],  lane0); t[10] = pv1;
        WAITX(x3); xissue(xb, sb, rb + 14, x2);
        sub(x3, rb + 11, y0, y1, ys0, ys1, pv0, pv1, o1, lb[11], lb[10], lane0); t[11] = pv1;
        WAITX(x0); xissue(xb, sb, rb + 15, x3);
        sub(x0, rb + 12, y0, y1, ys0, ys1, pv0, pv1, o1, lb[12], lb[11], lane0); t[12] = pv1;
        WAITX(x1); xissue(xb, sb, rb + 16, x0);
        sub(x1, rb + 13, y0, y1, ys0, ys1, pv0, pv1, o1, lb[13], lb[12], lane0); t[13] = pv1;
        WAITX(x2); xissue(xb, sb, rb + 17, x1);
        sub(x2, rb + 14, y0, y1, ys0, ys1, pv0, pv1, o1, lb[14], lb[13], lane0); t[14] = pv1;
        WAITX(x3); xissue(xb, sb, rb + 18, x2);
        sub(x3, rb + 15, y0, y1, ys0, ys1, pv0, pv1, o1, lb[15], lb[14], lane0); t[15] = pv1;

        carry = lb[15];

        if (l == 63 && W < 3) {
            pkt[e & 1][W][0] = f32x4{t[0],  t[1],  t[2],  t[3]};
            pkt[e & 1][W][1] = f32x4{t[4],  t[5],  t[6],  t[7]};
            pkt[e & 1][W][2] = f32x4{t[8],  t[9],  t[10], t[11]};
            pkt[e & 1][W][3] = f32x4{t[12], t[13], t[14], t[15]};
        }
        __syncthreads();
    }

    if (W == 3 && l == 63) ws[b] = sqrtf(pv1);   // DTW[511][511]
}

__global__ void dtw_reduce_kernel(const float* __restrict__ ws, float* __restrict__ out) {
    const int t = threadIdx.x;          // 64 threads
    float v = ws[t] + ws[t + 64];
    #pragma unroll
    for (int d2 = 32; d2 > 0; d2 >>= 1) v += __shfl_down(v, d2);
    if (t == 0) out[0] = v * (1.0f / TNB);
}

extern "C" void kernel_launch(void* const* d_in, const int* in_sizes, int n_in,
                              void* d_out, int out_size, void* d_ws, size_t ws_size,
                              hipStream_t stream) {
    const float* s1 = (const float*)d_in[0];
    const float* s2 = (const float*)d_in[1];
    float* ws  = (float*)d_ws;
    float* out = (float*)d_out;

    dtw_split_kernel<<<TNB, 256, 0, stream>>>(s1, s2, ws);
    dtw_reduce_kernel<<<1, 64, 0, stream>>>(ws, out);
}